// Round 10
// baseline (3895.808 us; speedup 1.0000x reference)
//
#include <hip/hip_runtime.h>
#include <hip/hip_bf16.h>

typedef __hip_bfloat16 bf16;
typedef unsigned short u16x8 __attribute__((ext_vector_type(8)));
using v8s = __attribute__((ext_vector_type(8))) short;   // bf16 x8 MFMA frag (4 VGPR)
using v4f = __attribute__((ext_vector_type(4))) float;   // f32 x4 acc frag

#define L_SEQ 2048
#define BATCH 8
#define NIN   1024    // 2H
#define WLD   3072    // W row stride, layers 1-3
#define NHALF 1536    // per-direction columns (3*H)
#define NROWS (L_SEQ*BATCH)

__device__ __forceinline__ float bits2f(unsigned short u){ return __uint_as_float(((unsigned)u)<<16); }
__device__ __forceinline__ float b2f(bf16 v){ return __bfloat162float(v); }
__device__ __forceinline__ bf16  f2b(float v){ return __float2bfloat16(v); }
__device__ __forceinline__ float sigm(float z){ return __fdividef(1.0f, 1.0f + __expf(-z)); }

__device__ __forceinline__ void gload16(const void* g, void* l){
    __builtin_amdgcn_global_load_lds((const __attribute__((address_space(1))) void*)g,
                                     (__attribute__((address_space(3))) void*)l, 16, 0, 0);
}

__global__ void k_code(float* __restrict__ out, float v){
    if (threadIdx.x == 0 && blockIdx.x == 0) out[0] = v;
}

// ---------------- dxT[b][l] = X[b][l] - X[b][l-1], 0 at l=0  ((B,L) layout)
__global__ __launch_bounds__(256) void k_diff(const float* __restrict__ X, float* __restrict__ dxT){
    int i = blockIdx.x*256 + threadIdx.x;
    if (i >= NROWS) return;
    int l = i & (L_SEQ-1);
    float v = 0.f;
    if (l > 0) v = X[i] - X[i-1];
    dxT[i] = v;
}

// ---------------- W (fp32 [1024][3072]) -> Wt (bf16 [3072][1024], transposed)
__global__ __launch_bounds__(256) void k_wt(const float* __restrict__ W, bf16* __restrict__ Wt){
    __shared__ float t[32][33];
    int k0 = blockIdx.x*32, n0 = blockIdx.y*32;
    int tx = threadIdx.x & 31, ty = threadIdx.x >> 5;   // ty 0..7
    #pragma unroll
    for (int j=0;j<4;j++)
        t[ty*4+j][tx] = W[(size_t)(k0+ty*4+j)*WLD + n0 + tx];
    __syncthreads();
    #pragma unroll
    for (int j=0;j<4;j++)
        Wt[(size_t)(n0+ty*4+j)*NIN + k0 + tx] = f2b(t[tx][ty*4+j]);
}

// ---------------- layer 0 (n_in=1, k=4): thread owns (b,h) for BOTH directions -> 2 independent
// chains interleave in the issue stream (fills dependent-latency stalls). 64 blocks x 64 threads.
__global__ __launch_bounds__(64) void k_layer0(const float* __restrict__ dxT, const float* __restrict__ W0,
                                               const float* __restrict__ wc, const float* __restrict__ bb,
                                               bf16* __restrict__ xout){
    __shared__ float sdx[L_SEQ];
    int g = blockIdx.x*64 + threadIdx.x;            // 4096 threads: (b,h)
    int h = g & 511, b = g >> 9;                    // b block-uniform
    const float* dxp = dxT + b*L_SEQ;
    for (int t = threadIdx.x; t < L_SEQ; t += 64) sdx[t] = dxp[t];
    __syncthreads();

    // fwd (dcol=h) / bwd (dcol=512+h) params
    float fw0 = W0[h],      fw1 = W0[512+h],      fw2 = W0[1024+h],      fw3 = W0[1536+h];
    float bw0 = W0[2048+h], bw1 = W0[2048+512+h], bw2 = W0[2048+1024+h], bw3 = W0[2048+1536+h];
    float vf0 = wc[h],     vr0 = wc[1024+h],     bf0 = bb[h],     br0 = bb[1024+h];
    float vf1 = wc[512+h], vr1 = wc[1536+h],     bf1 = bb[512+h], br1 = bb[1536+h];
    float c0 = 0.f, c1 = 0.f;

    bf16* xf = xout + (size_t)b*NIN + h;                                  // + s*8192
    bf16* xb_ = xout + ((size_t)(L_SEQ-1)*BATCH + b)*NIN + 512 + h;       // - s*8192

#define LD0(bf_, bb_, s0) do{                                        \
        _Pragma("unroll")                                            \
        for (int i_=0;i_<8;i_++){                                    \
            bf_[i_] = sdx[(s0)+i_];                                  \
            bb_[i_] = sdx[L_SEQ-1-((s0)+i_)];                        \
        }                                                            \
        __builtin_amdgcn_sched_barrier(0);                           \
    }while(0)

#define STEP0(s_, xf_, xb_v) do{                                     \
        float f0_ = sigm((xf_)*fw1 + vf0*c0 + bf0);                  \
        c0 = f0_*c0 + (1.f-f0_)*((xf_)*fw0);                         \
        float r0_ = sigm((xf_)*fw2 + vr0*c0 + br0);                  \
        float h0_ = r0_*c0 + (1.f-r0_)*((xf_)*fw3);                  \
        xf[(ptrdiff_t)(s_)*(BATCH*NIN)] = f2b(h0_);                  \
        float f1_ = sigm((xb_v)*bw1 + vf1*c1 + bf1);                 \
        c1 = f1_*c1 + (1.f-f1_)*((xb_v)*bw0);                        \
        float r1_ = sigm((xb_v)*bw2 + vr1*c1 + br1);                 \
        float h1_ = r1_*c1 + (1.f-r1_)*((xb_v)*bw3);                 \
        xb_[-(ptrdiff_t)(s_)*(BATCH*NIN)] = f2b(h1_);                \
    }while(0)

    float af[8], ab[8], bf_[8], bb_[8];
    LD0(af, ab, 0);
    for (int s0 = 0; s0 + 32 <= L_SEQ; s0 += 16){
        LD0(bf_, bb_, s0+8);
        #pragma unroll
        for (int i=0;i<8;i++) STEP0(s0+i, af[i], ab[i]);
        LD0(af, ab, s0+16);
        #pragma unroll
        for (int i=0;i<8;i++) STEP0(s0+8+i, bf_[i], bb_[i]);
    }
    LD0(bf_, bb_, L_SEQ-8);
    #pragma unroll
    for (int i=0;i<8;i++) STEP0(L_SEQ-16+i, af[i], ab[i]);
    #pragma unroll
    for (int i=0;i<8;i++) STEP0(L_SEQ-8+i, bf_[i], bb_[i]);
#undef LD0
#undef STEP0
}

// ---------------- MFMA GEMM: Uc[set s] = x[chunk rows] @ Wt[set s]^T  (unchanged: control)
__global__ __launch_bounds__(256) void k_gemm(const bf16* __restrict__ Xin, const bf16* __restrict__ Wt,
                                              float* __restrict__ Uc, int l0, int C){
    __shared__ bf16 As[2][4096];   // [buf][128 m][32 k], 64B rows
    __shared__ bf16 Bs[2][4096];
    int tid = threadIdx.x;
    int lane = tid & 63;
    int s = blockIdx.z;
    int base = (s == 0) ? l0 : (L_SEQ - l0 - C);
    const bf16* A  = Xin + (size_t)base*BATCH*NIN;
    const bf16* Bm = Wt + (size_t)s*NHALF*NIN;
    float*      Cc = Uc + (size_t)s*(size_t)C*BATCH*NHALF;

    int m0 = blockIdx.x*128, n0 = blockIdx.y*128;
    int wv = tid >> 6;
    int wm = (wv >> 1)*64, wn = (wv & 1)*64;

    v4f acc[4][4];
    #pragma unroll
    for (int i=0;i<4;i++)
        #pragma unroll
        for (int j=0;j<4;j++)
            #pragma unroll
            for (int r=0;r<4;r++) acc[i][j][r] = 0.f;

    int row_a = tid >> 2, kb = (tid & 3)*8;
    int wbase = (tid & 192)*16;
    int fro = (lane & 15)*64 + (lane >> 4)*16;

#define STAGE(q, k0) do{                                                        \
        char* la_ = (char*)As[q]; char* lb_ = (char*)Bs[q];                     \
        gload16(A  + (size_t)(m0 + row_a      )*NIN + (k0) + kb, la_ + wbase);  \
        gload16(A  + (size_t)(m0 + row_a + 64 )*NIN + (k0) + kb, la_ + 4096 + wbase); \
        gload16(Bm + (size_t)(n0 + row_a      )*NIN + (k0) + kb, lb_ + wbase);  \
        gload16(Bm + (size_t)(n0 + row_a + 64 )*NIN + (k0) + kb, lb_ + 4096 + wbase); \
    }while(0)

    STAGE(0, 0);
    __syncthreads();
    int cur = 0;
    for (int k0 = 0; k0 < NIN; k0 += 32){
        if (k0 + 32 < NIN) STAGE(cur^1, k0 + 32);
        __builtin_amdgcn_sched_barrier(0);
        const char* la = (const char*)As[cur];
        const char* lb = (const char*)Bs[cur];
        v8s av[4], bv[4];
        #pragma unroll
        for (int i=0;i<4;i++) av[i] = *(const v8s*)(la + (wm + i*16)*64 + fro);
        #pragma unroll
        for (int j=0;j<4;j++) bv[j] = *(const v8s*)(lb + (wn + j*16)*64 + fro);
        #pragma unroll
        for (int i=0;i<4;i++)
            #pragma unroll
            for (int j=0;j<4;j++)
                acc[i][j] = __builtin_amdgcn_mfma_f32_16x16x32_bf16(av[i], bv[j], acc[i][j], 0, 0, 0);
        __syncthreads();
        cur ^= 1;
    }
#undef STAGE

    int cr = (lane >> 4)*4, ccol = lane & 15;
    #pragma unroll
    for (int i=0;i<4;i++){
        #pragma unroll
        for (int j=0;j<4;j++){
            size_t rb = (size_t)(m0 + wm + i*16 + cr)*NHALF + (n0 + wn + j*16 + ccol);
            #pragma unroll
            for (int r=0;r<4;r++) Cc[rb + (size_t)r*NHALF] = acc[i][j][r];
        }
    }
}

// ---------------- recurrence, layers 1-3: thread owns (b,h) BOTH directions; pinned 8-ahead prefetch
__global__ __launch_bounds__(64) void k_rec(const float* __restrict__ Uc, const bf16* __restrict__ xin,
                                            bf16* __restrict__ xout, float* __restrict__ carry,
                                            const float* __restrict__ wc, const float* __restrict__ bb,
                                            int l0, int C){
    int g = blockIdx.x*64 + threadIdx.x;            // 4096 threads: (b,h)
    int h = g & 511, b = g >> 9;
    float vf0 = wc[h],     vr0 = wc[1024+h],  bf0 = bb[h],     br0 = bb[1024+h];
    float vf1 = wc[512+h], vr1 = wc[1536+h],  bf1 = bb[512+h], br1 = bb[1536+h];
    float c0 = (l0 == 0) ? 0.f : carry[g];
    float c1 = (l0 == 0) ? 0.f : carry[4096 + g];

    // U streams: fwd set 0 rows 0..C-1 (+12288/step); bwd set 1 rows C-1..0 (-12288/step)
    const float* uf = Uc + (size_t)b*NHALF + h;
    const float* ub = Uc + (size_t)C*12288 + (size_t)(C-1)*12288 + (size_t)b*NHALF + h;
    // x streams: fwd col h at t=l0+s (+8192/step); bwd col 512+h at t=L-1-l0-s (-8192/step)
    const bf16* xpf = xin  + ((size_t)l0*BATCH + b)*NIN + h;
    bf16*       xqf = xout + ((size_t)l0*BATCH + b)*NIN + h;
    const bf16* xpb = xin  + ((size_t)(L_SEQ-1-l0)*BATCH + b)*NIN + 512 + h;
    bf16*       xqb = xout + ((size_t)(L_SEQ-1-l0)*BATCH + b)*NIN + 512 + h;

#define LOADG(F0,F1,F2,FR,G0,G1,G2,GR,s0) do{                        \
        _Pragma("unroll")                                            \
        for (int i_=0;i_<8;i_++){                                    \
            const float* uf_ = uf + (ptrdiff_t)((s0)+i_)*12288;      \
            F0[i_]=uf_[0]; F1[i_]=uf_[512]; F2[i_]=uf_[1024];        \
            FR[i_]=b2f(xpf[(ptrdiff_t)((s0)+i_)*(BATCH*NIN)]);       \
            const float* ub_ = ub - (ptrdiff_t)((s0)+i_)*12288;      \
            G0[i_]=ub_[0]; G1[i_]=ub_[512]; G2[i_]=ub_[1024];        \
            GR[i_]=b2f(xpb[-(ptrdiff_t)((s0)+i_)*(BATCH*NIN)]);      \
        }                                                            \
        __builtin_amdgcn_sched_barrier(0);                           \
    }while(0)

#define STEPG(F0,F1,F2,FR,G0,G1,G2,GR,s0) do{                        \
        _Pragma("unroll")                                            \
        for (int i_=0;i_<8;i_++){                                    \
            float f0_ = sigm(F1[i_] + vf0*c0 + bf0);                 \
            c0 = f0_*c0 + (1.f-f0_)*F0[i_];                          \
            float r0_ = sigm(F2[i_] + vr0*c0 + br0);                 \
            float h0_ = r0_*c0 + (1.f-r0_)*FR[i_];                   \
            xqf[(ptrdiff_t)((s0)+i_)*(BATCH*NIN)] = f2b(h0_);        \
            float f1_ = sigm(G1[i_] + vf1*c1 + bf1);                 \
            c1 = f1_*c1 + (1.f-f1_)*G0[i_];                          \
            float r1_ = sigm(G2[i_] + vr1*c1 + br1);                 \
            float h1_ = r1_*c1 + (1.f-r1_)*GR[i_];                   \
            xqb[-(ptrdiff_t)((s0)+i_)*(BATCH*NIN)] = f2b(h1_);       \
        } }while(0)

    float A0[8],A1[8],A2[8],AR[8],Ag0[8],Ag1[8],Ag2[8],AgR[8];
    float B0[8],B1[8],B2[8],BR[8],Bg0[8],Bg1[8],Bg2[8],BgR[8];
    LOADG(A0,A1,A2,AR,Ag0,Ag1,Ag2,AgR, 0);
    for (int s0 = 0; s0 + 32 <= C; s0 += 16){
        LOADG(B0,B1,B2,BR,Bg0,Bg1,Bg2,BgR, s0+8);
        STEPG(A0,A1,A2,AR,Ag0,Ag1,Ag2,AgR, s0);
        LOADG(A0,A1,A2,AR,Ag0,Ag1,Ag2,AgR, s0+16);
        STEPG(B0,B1,B2,BR,Bg0,Bg1,Bg2,BgR, s0+8);
    }
    LOADG(B0,B1,B2,BR,Bg0,Bg1,Bg2,BgR, C-8);
    STEPG(A0,A1,A2,AR,Ag0,Ag1,Ag2,AgR, C-16);
    STEPG(B0,B1,B2,BR,Bg0,Bg1,Bg2,BgR, C-8);
    carry[g] = c0;
    carry[4096 + g] = c1;
#undef LOADG
#undef STEPG
}

// ---------------- classifier: out[(b*L + l)*3 + j] = h[row l*8+b] @ Wcls + bcls
__global__ __launch_bounds__(256) void k_cls(const bf16* __restrict__ Xf, const float* __restrict__ Wc,
                                             const float* __restrict__ bc, float* __restrict__ out){
    int wave = threadIdx.x >> 6, lane = threadIdx.x & 63;
    int row = blockIdx.x*4 + wave;                  // row = l*8+b
    const bf16* xp = Xf + (size_t)row*NIN + lane*16;
    u16x8 v0 = *(const u16x8*)(xp);
    u16x8 v1 = *(const u16x8*)(xp + 8);
    float a0=0.f, a1=0.f, a2=0.f;
    #pragma unroll
    for (int i=0;i<16;i++){
        float xv = bits2f(i<8 ? v0[i&7] : v1[i&7]);
        int k = lane*16 + i;
        a0 += xv*Wc[k*3+0];
        a1 += xv*Wc[k*3+1];
        a2 += xv*Wc[k*3+2];
    }
    #pragma unroll
    for (int off=32; off; off>>=1){
        a0 += __shfl_down(a0, off);
        a1 += __shfl_down(a1, off);
        a2 += __shfl_down(a2, off);
    }
    if (lane == 0){
        int l = row >> 3, b = row & 7;
        float* op = out + ((size_t)b*L_SEQ + l)*3;
        op[0] = a0 + bc[0];
        op[1] = a1 + bc[1];
        op[2] = a2 + bc[2];
    }
}

// ----------------------------------------------------------------
extern "C" void kernel_launch(void* const* d_in, const int* in_sizes, int n_in,
                              void* d_out, int out_size, void* d_ws, size_t ws_size,
                              hipStream_t stream){
    (void)in_sizes; (void)n_in; (void)out_size;
    const float* X    = (const float*)d_in[0];
    const float* W[4]  = {(const float*)d_in[1],(const float*)d_in[4],(const float*)d_in[7],(const float*)d_in[10]};
    const float* wc[4] = {(const float*)d_in[2],(const float*)d_in[5],(const float*)d_in[8],(const float*)d_in[11]};
    const float* bb[4] = {(const float*)d_in[3],(const float*)d_in[6],(const float*)d_in[9],(const float*)d_in[12]};
    const float* Wcls = (const float*)d_in[13];
    const float* bcls = (const float*)d_in[14];
    float* out = (float*)d_out;

    // workspace layout:
    //   xA    bf16[16384*1024]  @ 0           33,554,432
    //   xB    bf16[16384*1024]  @ 33554432    33,554,432
    //   dxT   f32 [8*2048]      @ 67108864        65,536
    //   carry f32 [8192]        @ 67174400        32,768
    //   Wt0-2 bf16[3072*1024]   @ 67207168    3 x 6,291,456
    //   Ucb   f32 [C*2*8*1536]  @ 86081536    C*98,304   (C: 64..2048)
    char*  ws    = (char*)d_ws;
    bf16*  xA    = (bf16*)ws;
    bf16*  xB    = (bf16*)(ws + 33554432);
    float* dxT   = (float*)(ws + 67108864);
    float* carry = (float*)(ws + 67174400);
    bf16*  Wt[3] = {(bf16*)(ws + 67207168), (bf16*)(ws + 73498624), (bf16*)(ws + 79790080)};
    float* Ucb   = (float*)(ws + 86081536);
    const size_t NEEDED = 86081536ull + 64ull*98304ull;

    if (ws_size < NEEDED){
        float code = 1.0e6f + (float)((ws_size >> 20) > 9999 ? 9999 : (ws_size >> 20)) * 100.0f;
        k_code<<<1, 64, 0, stream>>>(out, code);
        return;
    }

    int C = 2048;
    while (C > 64 && 86081536ull + (size_t)C*98304ull > ws_size) C >>= 1;

    k_diff  <<<(NROWS+255)/256, 256, 0, stream>>>(X, dxT);
    for (int i = 0; i < 3; ++i)
        k_wt<<<dim3(32,96), 256, 0, stream>>>(W[i+1], Wt[i]);
    k_layer0<<<64, 64, 0, stream>>>(dxT, W[0], wc[0], bb[0], xA);

    bf16* xin = xA; bf16* xo = xB;
    for (int layer = 1; layer < 4; ++layer){
        for (int l0 = 0; l0 < L_SEQ; l0 += C){
            dim3 g(C*8/128, NHALF/128, 2);
            k_gemm<<<g, 256, 0, stream>>>(xin, Wt[layer-1], Ucb, l0, C);
            k_rec <<<64, 64, 0, stream>>>(Ucb, xin, xo, carry, wc[layer], bb[layer], l0, C);
        }
        bf16* t = xin; xin = xo; xo = t;
    }
    k_cls<<<NROWS/4, 256, 0, stream>>>(xin, Wcls, bcls, out);
}

// Round 11
// 1928.368 us; speedup vs baseline: 2.0203x; 2.0203x over previous
//
#include <hip/hip_runtime.h>
#include <hip/hip_bf16.h>

typedef __hip_bfloat16 bf16;
typedef unsigned short u16x8 __attribute__((ext_vector_type(8)));
using v8s = __attribute__((ext_vector_type(8))) short;   // bf16 x8 MFMA frag (4 VGPR)
using v4f = __attribute__((ext_vector_type(4))) float;   // f32 x4 acc frag

#define L_SEQ 2048
#define BATCH 8
#define NIN   1024    // 2H
#define WLD   3072    // W row stride, layers 1-3
#define NHALF 1536    // per-direction columns (3*H)
#define NROWS (L_SEQ*BATCH)

__device__ __forceinline__ float bits2f(unsigned short u){ return __uint_as_float(((unsigned)u)<<16); }
__device__ __forceinline__ float b2f(bf16 v){ return __bfloat162float(v); }
__device__ __forceinline__ bf16  f2b(float v){ return __float2bfloat16(v); }
__device__ __forceinline__ float sigm(float z){ return __fdividef(1.0f, 1.0f + __expf(-z)); }

__device__ __forceinline__ void gload16(const void* g, void* l){
    __builtin_amdgcn_global_load_lds((const __attribute__((address_space(1))) void*)g,
                                     (__attribute__((address_space(3))) void*)l, 16, 0, 0);
}

__global__ void k_code(float* __restrict__ out, float v){
    if (threadIdx.x == 0 && blockIdx.x == 0) out[0] = v;
}

// ---------------- dxT[b][l] = X[b][l] - X[b][l-1], 0 at l=0  ((B,L) layout)
__global__ __launch_bounds__(256) void k_diff(const float* __restrict__ X, float* __restrict__ dxT){
    int i = blockIdx.x*256 + threadIdx.x;
    if (i >= NROWS) return;
    int l = i & (L_SEQ-1);
    float v = 0.f;
    if (l > 0) v = X[i] - X[i-1];
    dxT[i] = v;
}

// ---------------- W (fp32 [1024][3072]) -> Wt (bf16 [3072][1024], transposed)
__global__ __launch_bounds__(256) void k_wt(const float* __restrict__ W, bf16* __restrict__ Wt){
    __shared__ float t[32][33];
    int k0 = blockIdx.x*32, n0 = blockIdx.y*32;
    int tx = threadIdx.x & 31, ty = threadIdx.x >> 5;   // ty 0..7
    #pragma unroll
    for (int j=0;j<4;j++)
        t[ty*4+j][tx] = W[(size_t)(k0+ty*4+j)*WLD + n0 + tx];
    __syncthreads();
    #pragma unroll
    for (int j=0;j<4;j++)
        Wt[(size_t)(n0+ty*4+j)*NIN + k0 + tx] = f2b(t[tx][ty*4+j]);
}

// ---------------- layer 0: thread owns channels (2hp, 2hp+1) of ONE direction:
// 2 independent chains share one sdx read and one packed 4B store per step.
__global__ __launch_bounds__(64) void k_layer0(const float* __restrict__ dxT, const float* __restrict__ W0,
                                               const float* __restrict__ wc, const float* __restrict__ bb,
                                               bf16* __restrict__ xout){
    __shared__ float sdx[L_SEQ];
    int tid = threadIdx.x, bid = blockIdx.x;        // 64 blocks x 64 threads
    int d = bid >> 5, b = (bid >> 2) & 7;
    int hp2 = ((bid & 3)*64 + tid)*2;               // even h in [0,512)
    const float* dxp = dxT + b*L_SEQ;
    for (int t = tid; t < L_SEQ; t += 64) sdx[t] = dxp[t];
    __syncthreads();

    int dcol = d*512 + hp2;
    const float* Wd = W0 + d*2048;
    float w0a=Wd[hp2],      w0b=Wd[hp2+1];
    float w1a=Wd[512+hp2],  w1b=Wd[513+hp2];
    float w2a=Wd[1024+hp2], w2b=Wd[1025+hp2];
    float w3a=Wd[1536+hp2], w3b=Wd[1537+hp2];
    float vfa=wc[d*512+hp2],      vfb=wc[d*512+hp2+1];
    float vra=wc[1024+d*512+hp2], vrb=wc[1025+d*512+hp2];
    float bfa=bb[d*512+hp2],      bfb=bb[d*512+hp2+1];
    float bra=bb[1024+d*512+hp2], brb=bb[1025+d*512+hp2];
    float c0=0.f, c1=0.f;
    char* outbase = (char*)(xout + (size_t)b*NIN + dcol);   // + t*16384 bytes

#define LD0(buf, s0) do{                                             \
        _Pragma("unroll")                                            \
        for (int i_=0;i_<8;i_++){                                    \
            int ss_ = (s0)+i_; if (ss_ > L_SEQ-1) ss_ = L_SEQ-1;     \
            buf[i_] = sdx[d ? (L_SEQ-1-ss_) : ss_];                  \
        }                                                            \
        __builtin_amdgcn_sched_barrier(0);                           \
    }while(0)

#define STEP0(s_, xv_) do{                                           \
        float f0=sigm((xv_)*w1a + vfa*c0 + bfa);                     \
        c0 = f0*c0 + (1.f-f0)*((xv_)*w0a);                           \
        float r0=sigm((xv_)*w2a + vra*c0 + bra);                     \
        float h0 = r0*c0 + (1.f-r0)*((xv_)*w3a);                     \
        float f1=sigm((xv_)*w1b + vfb*c1 + bfb);                     \
        c1 = f1*c1 + (1.f-f1)*((xv_)*w0b);                           \
        float r1=sigm((xv_)*w2b + vrb*c1 + brb);                     \
        float h1 = r1*c1 + (1.f-r1)*((xv_)*w3b);                     \
        bf16 ta=f2b(h0), tb=f2b(h1);                                 \
        unsigned pk = (unsigned)(*(unsigned short*)&ta)              \
                    | ((unsigned)(*(unsigned short*)&tb) << 16);     \
        int t_ = d ? (L_SEQ-1-(s_)) : (s_);                          \
        *(unsigned*)(outbase + (size_t)t_*(BATCH*NIN*2)) = pk;       \
    }while(0)

    float xa[8], xb2[8];
    LD0(xa, 0);
    for (int s0 = 0; s0 + 32 <= L_SEQ; s0 += 16){
        LD0(xb2, s0+8);
        #pragma unroll
        for (int i=0;i<8;i++) STEP0(s0+i, xa[i]);
        LD0(xa, s0+16);
        #pragma unroll
        for (int i=0;i<8;i++) STEP0(s0+8+i, xb2[i]);
    }
    LD0(xb2, L_SEQ-8);
    #pragma unroll
    for (int i=0;i<8;i++) STEP0(L_SEQ-16+i, xa[i]);
    #pragma unroll
    for (int i=0;i<8;i++) STEP0(L_SEQ-8+i, xb2[i]);
#undef LD0
#undef STEP0
}

// ---------------- MFMA GEMM: Uc[set s] = x[chunk rows] @ Wt[set s]^T  (unchanged: control)
__global__ __launch_bounds__(256) void k_gemm(const bf16* __restrict__ Xin, const bf16* __restrict__ Wt,
                                              float* __restrict__ Uc, int l0, int C){
    __shared__ bf16 As[2][4096];   // [buf][128 m][32 k], 64B rows
    __shared__ bf16 Bs[2][4096];
    int tid = threadIdx.x;
    int lane = tid & 63;
    int s = blockIdx.z;
    int base = (s == 0) ? l0 : (L_SEQ - l0 - C);
    const bf16* A  = Xin + (size_t)base*BATCH*NIN;
    const bf16* Bm = Wt + (size_t)s*NHALF*NIN;
    float*      Cc = Uc + (size_t)s*(size_t)C*BATCH*NHALF;

    int m0 = blockIdx.x*128, n0 = blockIdx.y*128;
    int wv = tid >> 6;
    int wm = (wv >> 1)*64, wn = (wv & 1)*64;

    v4f acc[4][4];
    #pragma unroll
    for (int i=0;i<4;i++)
        #pragma unroll
        for (int j=0;j<4;j++)
            #pragma unroll
            for (int r=0;r<4;r++) acc[i][j][r] = 0.f;

    int row_a = tid >> 2, kb = (tid & 3)*8;
    int wbase = (tid & 192)*16;
    int fro = (lane & 15)*64 + (lane >> 4)*16;

#define STAGE(q, k0) do{                                                        \
        char* la_ = (char*)As[q]; char* lb_ = (char*)Bs[q];                     \
        gload16(A  + (size_t)(m0 + row_a      )*NIN + (k0) + kb, la_ + wbase);  \
        gload16(A  + (size_t)(m0 + row_a + 64 )*NIN + (k0) + kb, la_ + 4096 + wbase); \
        gload16(Bm + (size_t)(n0 + row_a      )*NIN + (k0) + kb, lb_ + wbase);  \
        gload16(Bm + (size_t)(n0 + row_a + 64 )*NIN + (k0) + kb, lb_ + 4096 + wbase); \
    }while(0)

    STAGE(0, 0);
    __syncthreads();
    int cur = 0;
    for (int k0 = 0; k0 < NIN; k0 += 32){
        if (k0 + 32 < NIN) STAGE(cur^1, k0 + 32);
        __builtin_amdgcn_sched_barrier(0);
        const char* la = (const char*)As[cur];
        const char* lb = (const char*)Bs[cur];
        v8s av[4], bv[4];
        #pragma unroll
        for (int i=0;i<4;i++) av[i] = *(const v8s*)(la + (wm + i*16)*64 + fro);
        #pragma unroll
        for (int j=0;j<4;j++) bv[j] = *(const v8s*)(lb + (wn + j*16)*64 + fro);
        #pragma unroll
        for (int i=0;i<4;i++)
            #pragma unroll
            for (int j=0;j<4;j++)
                acc[i][j] = __builtin_amdgcn_mfma_f32_16x16x32_bf16(av[i], bv[j], acc[i][j], 0, 0, 0);
        __syncthreads();
        cur ^= 1;
    }
#undef STAGE

    int cr = (lane >> 4)*4, ccol = lane & 15;
    #pragma unroll
    for (int i=0;i<4;i++){
        #pragma unroll
        for (int j=0;j<4;j++){
            size_t rb = (size_t)(m0 + wm + i*16 + cr)*NHALF + (n0 + wn + j*16 + ccol);
            #pragma unroll
            for (int r=0;r<4;r++) Cc[rb + (size_t)r*NHALF] = acc[i][j][r];
        }
    }
}

// ---------------- recurrence, layers 1-3: LDS-staged U/x via global_load_lds.
// 32 blocks x 256 threads; block owns (d, b, 256-h slice). Per 8-step group:
// stage 24KB U + 4KB x coalesced, counted vmcnt keeps next group's loads in flight.
__global__ __launch_bounds__(256) void k_rec(const float* __restrict__ Uc, const bf16* __restrict__ xin,
                                             bf16* __restrict__ xout, float* __restrict__ carry,
                                             const float* __restrict__ wc, const float* __restrict__ bb,
                                             int l0, int C){
    __shared__ float Ub[2][6144];   // [buf][seg=step*3+gate][256 floats]  2x24KB
    __shared__ bf16  Xb[2][2048];   // [buf][step][256 bf16]               2x4KB
    int tid = threadIdx.x;
    int lane = tid & 63, wv = tid >> 6;
    int bid = blockIdx.x;
    int d = bid >> 4, b = (bid >> 1) & 7, hbase = (bid & 1)*256;
    int h = hbase + tid;                 // tid<256 -> h in [hbase, hbase+256)
    int dcol = d*512 + h;
    int ch = d*4096 + b*512 + h;
    float vf = wc[d*512 + h], vr = wc[1024 + d*512 + h];
    float bfv = bb[d*512 + h], brv = bb[1024 + d*512 + h];
    float c = (l0 == 0) ? 0.f : carry[ch];

    const float* Ubase = Uc + (size_t)d*(size_t)C*12288 + b*1536 + hbase;

#define RSTAGE(base_, q_) do{                                                   \
        char* ub_ = (char*)Ub[q_]; char* xb_ = (char*)Xb[q_];                   \
        _Pragma("unroll")                                                       \
        for (int qq=0; qq<6; ++qq){                                             \
            int seg = qq*4 + wv;                                                \
            int st_ = seg/3, gate_ = seg - st_*3;                               \
            int ss_ = (base_) + st_;                                            \
            int row_ = d ? (C-1-ss_) : ss_;                                     \
            gload16(Ubase + (size_t)row_*12288 + gate_*512 + lane*4,            \
                    ub_ + seg*1024);                                            \
        }                                                                       \
        {   int st_ = (base_) + 2*wv + (lane>>5);                               \
            int t_  = d ? (L_SEQ-1 - l0 - st_) : (l0 + st_);                    \
            gload16(xin + ((size_t)t_*BATCH + b)*NIN + d*512 + hbase + (lane&31)*8, \
                    xb_ + wv*1024);                                             \
        }                                                                       \
    }while(0)

#define RCOMP(base_, q_) do{                                                    \
        float u0[8],u1[8],u2[8],xr[8];                                          \
        _Pragma("unroll")                                                       \
        for (int i_=0;i_<8;i_++){                                               \
            u0[i_]=Ub[q_][(i_*3+0)*256+tid]; u1[i_]=Ub[q_][(i_*3+1)*256+tid];   \
            u2[i_]=Ub[q_][(i_*3+2)*256+tid]; xr[i_]=b2f(Xb[q_][i_*256+tid]);    \
        }                                                                       \
        __builtin_amdgcn_sched_barrier(0);                                      \
        _Pragma("unroll")                                                       \
        for (int i_=0;i_<8;i_++){                                               \
            int ss_=(base_)+i_;                                                 \
            int t_ = d ? (L_SEQ-1-l0-ss_) : (l0+ss_);                           \
            float f_=sigm(u1[i_] + vf*c + bfv);                                 \
            c = f_*c + (1.f-f_)*u0[i_];                                         \
            float r_=sigm(u2[i_] + vr*c + brv);                                 \
            xout[((size_t)t_*BATCH + b)*NIN + dcol] = f2b(r_*c + (1.f-r_)*xr[i_]); \
        }                                                                       \
    }while(0)

    RSTAGE(0, 0);
    asm volatile("s_waitcnt vmcnt(0)" ::: "memory");
    __builtin_amdgcn_sched_barrier(0);
    __builtin_amdgcn_s_barrier();
    int ngrp = C >> 3;
    for (int g = 0; g < ngrp; ++g){
        int q = g & 1;
        if (g + 1 < ngrp){
            RSTAGE((g+1)*8, q^1);
            asm volatile("s_waitcnt vmcnt(15)" ::: "memory");   // 8 stores(prev) + 7 loads(next) may remain
        } else {
            asm volatile("s_waitcnt vmcnt(8)" ::: "memory");    // 8 stores(prev) may remain
        }
        __builtin_amdgcn_sched_barrier(0);
        __builtin_amdgcn_s_barrier();      // stage(g) resident for all waves
        RCOMP(g*8, q);
        __builtin_amdgcn_s_barrier();      // all waves done reading buf q before it's restaged
    }
    carry[ch] = c;
#undef RSTAGE
#undef RCOMP
}

// ---------------- classifier: out[(b*L + l)*3 + j] = h[row l*8+b] @ Wcls + bcls
__global__ __launch_bounds__(256) void k_cls(const bf16* __restrict__ Xf, const float* __restrict__ Wc,
                                             const float* __restrict__ bc, float* __restrict__ out){
    int wave = threadIdx.x >> 6, lane = threadIdx.x & 63;
    int row = blockIdx.x*4 + wave;                  // row = l*8+b
    const bf16* xp = Xf + (size_t)row*NIN + lane*16;
    u16x8 v0 = *(const u16x8*)(xp);
    u16x8 v1 = *(const u16x8*)(xp + 8);
    float a0=0.f, a1=0.f, a2=0.f;
    #pragma unroll
    for (int i=0;i<16;i++){
        float xv = bits2f(i<8 ? v0[i&7] : v1[i&7]);
        int k = lane*16 + i;
        a0 += xv*Wc[k*3+0];
        a1 += xv*Wc[k*3+1];
        a2 += xv*Wc[k*3+2];
    }
    #pragma unroll
    for (int off=32; off; off>>=1){
        a0 += __shfl_down(a0, off);
        a1 += __shfl_down(a1, off);
        a2 += __shfl_down(a2, off);
    }
    if (lane == 0){
        int l = row >> 3, b = row & 7;
        float* op = out + ((size_t)b*L_SEQ + l)*3;
        op[0] = a0 + bc[0];
        op[1] = a1 + bc[1];
        op[2] = a2 + bc[2];
    }
}

// ----------------------------------------------------------------
extern "C" void kernel_launch(void* const* d_in, const int* in_sizes, int n_in,
                              void* d_out, int out_size, void* d_ws, size_t ws_size,
                              hipStream_t stream){
    (void)in_sizes; (void)n_in; (void)out_size;
    const float* X    = (const float*)d_in[0];
    const float* W[4]  = {(const float*)d_in[1],(const float*)d_in[4],(const float*)d_in[7],(const float*)d_in[10]};
    const float* wc[4] = {(const float*)d_in[2],(const float*)d_in[5],(const float*)d_in[8],(const float*)d_in[11]};
    const float* bb[4] = {(const float*)d_in[3],(const float*)d_in[6],(const float*)d_in[9],(const float*)d_in[12]};
    const float* Wcls = (const float*)d_in[13];
    const float* bcls = (const float*)d_in[14];
    float* out = (float*)d_out;

    // workspace layout:
    //   xA    bf16[16384*1024]  @ 0           33,554,432
    //   xB    bf16[16384*1024]  @ 33554432    33,554,432
    //   dxT   f32 [8*2048]      @ 67108864        65,536
    //   carry f32 [8192]        @ 67174400        32,768
    //   Wt0-2 bf16[3072*1024]   @ 67207168    3 x 6,291,456
    //   Ucb   f32 [C*2*8*1536]  @ 86081536    C*98,304   (C: 64..2048)
    char*  ws    = (char*)d_ws;
    bf16*  xA    = (bf16*)ws;
    bf16*  xB    = (bf16*)(ws + 33554432);
    float* dxT   = (float*)(ws + 67108864);
    float* carry = (float*)(ws + 67174400);
    bf16*  Wt[3] = {(bf16*)(ws + 67207168), (bf16*)(ws + 73498624), (bf16*)(ws + 79790080)};
    float* Ucb   = (float*)(ws + 86081536);
    const size_t NEEDED = 86081536ull + 64ull*98304ull;

    if (ws_size < NEEDED){
        float code = 1.0e6f + (float)((ws_size >> 20) > 9999 ? 9999 : (ws_size >> 20)) * 100.0f;
        k_code<<<1, 64, 0, stream>>>(out, code);
        return;
    }

    int C = 2048;
    while (C > 64 && 86081536ull + (size_t)C*98304ull > ws_size) C >>= 1;

    k_diff  <<<(NROWS+255)/256, 256, 0, stream>>>(X, dxT);
    for (int i = 0; i < 3; ++i)
        k_wt<<<dim3(32,96), 256, 0, stream>>>(W[i+1], Wt[i]);
    k_layer0<<<64, 64, 0, stream>>>(dxT, W[0], wc[0], bb[0], xA);

    bf16* xin = xA; bf16* xo = xB;
    for (int layer = 1; layer < 4; ++layer){
        for (int l0 = 0; l0 < L_SEQ; l0 += C){
            dim3 g(C*8/128, NHALF/128, 2);
            k_gemm<<<g, 256, 0, stream>>>(xin, Wt[layer-1], Ucb, l0, C);
            k_rec <<<32, 256, 0, stream>>>(Ucb, xin, xo, carry, wc[layer], bb[layer], l0, C);
        }
        bf16* t = xin; xin = xo; xo = t;
    }
    k_cls<<<NROWS/4, 256, 0, stream>>>(xin, Wcls, bcls, out);
}

// Round 12
// 1836.382 us; speedup vs baseline: 2.1215x; 1.0501x over previous
//
#include <hip/hip_runtime.h>
#include <hip/hip_bf16.h>

typedef __hip_bfloat16 bf16;
typedef unsigned short u16x8 __attribute__((ext_vector_type(8)));
using v8s = __attribute__((ext_vector_type(8))) short;   // bf16 x8 MFMA frag (4 VGPR)
using v4f = __attribute__((ext_vector_type(4))) float;   // f32 x4 acc frag

#define L_SEQ 2048
#define BATCH 8
#define NIN   1024    // 2H
#define WLD   3072    // W row stride, layers 1-3
#define NHALF 1536    // per-direction columns (3*H)
#define NROWS (L_SEQ*BATCH)

__device__ __forceinline__ float bits2f(unsigned short u){ return __uint_as_float(((unsigned)u)<<16); }
__device__ __forceinline__ float b2f(bf16 v){ return __bfloat162float(v); }
__device__ __forceinline__ bf16  f2b(float v){ return __float2bfloat16(v); }
__device__ __forceinline__ float sigm(float z){ return __fdividef(1.0f, 1.0f + __expf(-z)); }

__device__ __forceinline__ void gload16(const void* g, void* l){
    __builtin_amdgcn_global_load_lds((const __attribute__((address_space(1))) void*)g,
                                     (__attribute__((address_space(3))) void*)l, 16, 0, 0);
}

__global__ void k_code(float* __restrict__ out, float v){
    if (threadIdx.x == 0 && blockIdx.x == 0) out[0] = v;
}

// ---------------- dxT[b][l] = X[b][l] - X[b][l-1], 0 at l=0  ((B,L) layout)
__global__ __launch_bounds__(256) void k_diff(const float* __restrict__ X, float* __restrict__ dxT){
    int i = blockIdx.x*256 + threadIdx.x;
    if (i >= NROWS) return;
    int l = i & (L_SEQ-1);
    float v = 0.f;
    if (l > 0) v = X[i] - X[i-1];
    dxT[i] = v;
}

// ---------------- W (fp32 [1024][3072]) -> Wt (bf16 [3072][1024], transposed)
__global__ __launch_bounds__(256) void k_wt(const float* __restrict__ W, bf16* __restrict__ Wt){
    __shared__ float t[32][33];
    int k0 = blockIdx.x*32, n0 = blockIdx.y*32;
    int tx = threadIdx.x & 31, ty = threadIdx.x >> 5;   // ty 0..7
    #pragma unroll
    for (int j=0;j<4;j++)
        t[ty*4+j][tx] = W[(size_t)(k0+ty*4+j)*WLD + n0 + tx];
    __syncthreads();
    #pragma unroll
    for (int j=0;j<4;j++)
        Wt[(size_t)(n0+ty*4+j)*NIN + k0 + tx] = f2b(t[tx][ty*4+j]);
}

// ---------------- layer 0 (n_in=1, k=4): REVERTED to measured-252us round-7 version.
// 32 blocks x 256 threads (128 waves = 128 SIMDs); 1 channel/thread; pinned 8-ahead prefetch.
__global__ __launch_bounds__(256) void k_layer0(const float* __restrict__ dxT, const float* __restrict__ W0,
                                                const float* __restrict__ wc, const float* __restrict__ bb,
                                                bf16* __restrict__ xout){
    __shared__ float sdx[L_SEQ];
    int g = blockIdx.x*256 + threadIdx.x;           // 8192 threads: (d,b,h); b,d block-uniform
    int h = g & 511, b = (g>>9) & 7, d = g >> 12;
    const float* dxp = dxT + b*L_SEQ;
    for (int t = threadIdx.x; t < L_SEQ; t += 256) sdx[t] = dxp[t];
    __syncthreads();

    int dcol = d*512 + h;
    float w0 = W0[d*2048 + h];
    float w1 = W0[d*2048 + 512 + h];
    float w2 = W0[d*2048 + 1024 + h];
    float w3 = W0[d*2048 + 1536 + h];
    float vf = wc[dcol],  vr = wc[1024 + dcol];
    float bfv = bb[dcol], brv = bb[1024 + dcol];
    float c = 0.f;

#define LD0(buf, s0) do{                                             \
        _Pragma("unroll")                                            \
        for (int i_=0;i_<8;i_++){                                    \
            int ss_ = (s0)+i_; if (ss_ > L_SEQ-1) ss_ = L_SEQ-1;     \
            buf[i_] = sdx[d ? (L_SEQ-1-ss_) : ss_];                  \
        }                                                            \
        __builtin_amdgcn_sched_barrier(0);                           \
    }while(0)

#define STEP0(s_, xv_) do{                                           \
        float u0_ = (xv_)*w0;                                        \
        float f_ = sigm((xv_)*w1 + vf*c + bfv);                      \
        c = f_*c + (1.f-f_)*u0_;                                     \
        float r_ = sigm((xv_)*w2 + vr*c + brv);                      \
        float hv_ = r_*c + (1.f-r_)*((xv_)*w3);                      \
        int t_ = d ? (L_SEQ-1-(s_)) : (s_);                          \
        xout[((size_t)t_*BATCH + b)*NIN + dcol] = f2b(hv_);          \
    }while(0)

    float xa[8], xb[8];
    LD0(xa, 0);
    for (int s0 = 0; s0 < L_SEQ; s0 += 16){
        LD0(xb, s0+8);
        #pragma unroll
        for (int i=0;i<8;i++) STEP0(s0+i, xa[i]);
        LD0(xa, s0+16);
        #pragma unroll
        for (int i=0;i<8;i++) STEP0(s0+8+i, xb[i]);
    }
#undef LD0
#undef STEP0
}

// ---------------- MFMA GEMM: Uc[set s] = x[chunk rows] @ Wt[set s]^T
// 128x128 tile, BK=32, 4 waves; 2-phase dbuf with COUNTED vmcnt: prefetch of tile k+1
// stays in flight across the barrier (vmcnt(4)); only the last iter drains to 0.
__global__ __launch_bounds__(256) void k_gemm(const bf16* __restrict__ Xin, const bf16* __restrict__ Wt,
                                              float* __restrict__ Uc, int l0, int C){
    __shared__ bf16 As[2][4096];   // [buf][128 m][32 k], 64B rows
    __shared__ bf16 Bs[2][4096];
    int tid = threadIdx.x;
    int lane = tid & 63;
    int s = blockIdx.z;
    int base = (s == 0) ? l0 : (L_SEQ - l0 - C);
    const bf16* A  = Xin + (size_t)base*BATCH*NIN;
    const bf16* Bm = Wt + (size_t)s*NHALF*NIN;
    float*      Cc = Uc + (size_t)s*(size_t)C*BATCH*NHALF;

    int m0 = blockIdx.x*128, n0 = blockIdx.y*128;
    int wv = tid >> 6;
    int wm = (wv >> 1)*64, wn = (wv & 1)*64;

    v4f acc[4][4];
    #pragma unroll
    for (int i=0;i<4;i++)
        #pragma unroll
        for (int j=0;j<4;j++)
            #pragma unroll
            for (int r=0;r<4;r++) acc[i][j][r] = 0.f;

    int row_a = tid >> 2, kb = (tid & 3)*8;
    int wbase = (tid & 192)*16;
    int fro = (lane & 15)*64 + (lane >> 4)*16;

#define STAGE(q, k0) do{                                                        \
        char* la_ = (char*)As[q]; char* lb_ = (char*)Bs[q];                     \
        gload16(A  + (size_t)(m0 + row_a      )*NIN + (k0) + kb, la_ + wbase);  \
        gload16(A  + (size_t)(m0 + row_a + 64 )*NIN + (k0) + kb, la_ + 4096 + wbase); \
        gload16(Bm + (size_t)(n0 + row_a      )*NIN + (k0) + kb, lb_ + wbase);  \
        gload16(Bm + (size_t)(n0 + row_a + 64 )*NIN + (k0) + kb, lb_ + 4096 + wbase); \
    }while(0)

    STAGE(0, 0);
    int cur = 0;
    for (int k0 = 0; k0 < NIN; k0 += 32){
        if (k0 + 32 < NIN){
            STAGE(cur^1, k0 + 32);                              // 4 prefetch loads in flight
            asm volatile("s_waitcnt vmcnt(4)" ::: "memory");    // drain only tile-k loads
        } else {
            asm volatile("s_waitcnt vmcnt(0)" ::: "memory");
        }
        __builtin_amdgcn_sched_barrier(0);
        __builtin_amdgcn_s_barrier();      // tile k resident for all waves
        const char* la = (const char*)As[cur];
        const char* lb = (const char*)Bs[cur];
        v8s av[4], bv[4];
        #pragma unroll
        for (int i=0;i<4;i++) av[i] = *(const v8s*)(la + (wm + i*16)*64 + fro);
        #pragma unroll
        for (int j=0;j<4;j++) bv[j] = *(const v8s*)(lb + (wn + j*16)*64 + fro);
        #pragma unroll
        for (int i=0;i<4;i++)
            #pragma unroll
            for (int j=0;j<4;j++)
                acc[i][j] = __builtin_amdgcn_mfma_f32_16x16x32_bf16(av[i], bv[j], acc[i][j], 0, 0, 0);
        __builtin_amdgcn_s_barrier();      // all reads of buf cur done before next restage
        cur ^= 1;
    }
#undef STAGE

    int cr = (lane >> 4)*4, ccol = lane & 15;
    #pragma unroll
    for (int i=0;i<4;i++){
        #pragma unroll
        for (int j=0;j<4;j++){
            size_t rb = (size_t)(m0 + wm + i*16 + cr)*NHALF + (n0 + wn + j*16 + ccol);
            #pragma unroll
            for (int r=0;r<4;r++) Cc[rb + (size_t)r*NHALF] = acc[i][j][r];
        }
    }
}

// ---------------- recurrence, layers 1-3: LDS-staged U/x via global_load_lds (round-11, validated)
__global__ __launch_bounds__(256) void k_rec(const float* __restrict__ Uc, const bf16* __restrict__ xin,
                                             bf16* __restrict__ xout, float* __restrict__ carry,
                                             const float* __restrict__ wc, const float* __restrict__ bb,
                                             int l0, int C){
    __shared__ float Ub[2][6144];   // [buf][seg=step*3+gate][256 floats]  2x24KB
    __shared__ bf16  Xb[2][2048];   // [buf][step][256 bf16]               2x4KB
    int tid = threadIdx.x;
    int lane = tid & 63, wv = tid >> 6;
    int bid = blockIdx.x;
    int d = bid >> 4, b = (bid >> 1) & 7, hbase = (bid & 1)*256;
    int h = hbase + tid;
    int dcol = d*512 + h;
    int ch = d*4096 + b*512 + h;
    float vf = wc[d*512 + h], vr = wc[1024 + d*512 + h];
    float bfv = bb[d*512 + h], brv = bb[1024 + d*512 + h];
    float c = (l0 == 0) ? 0.f : carry[ch];

    const float* Ubase = Uc + (size_t)d*(size_t)C*12288 + b*1536 + hbase;

#define RSTAGE(base_, q_) do{                                                   \
        char* ub_ = (char*)Ub[q_]; char* xb_ = (char*)Xb[q_];                   \
        _Pragma("unroll")                                                       \
        for (int qq=0; qq<6; ++qq){                                             \
            int seg = qq*4 + wv;                                                \
            int st_ = seg/3, gate_ = seg - st_*3;                               \
            int ss_ = (base_) + st_;                                            \
            int row_ = d ? (C-1-ss_) : ss_;                                     \
            gload16(Ubase + (size_t)row_*12288 + gate_*512 + lane*4,            \
                    ub_ + seg*1024);                                            \
        }                                                                       \
        {   int st_ = (base_) + 2*wv + (lane>>5);                               \
            int t_  = d ? (L_SEQ-1 - l0 - st_) : (l0 + st_);                    \
            gload16(xin + ((size_t)t_*BATCH + b)*NIN + d*512 + hbase + (lane&31)*8, \
                    xb_ + wv*1024);                                             \
        }                                                                       \
    }while(0)

#define RCOMP(base_, q_) do{                                                    \
        float u0[8],u1[8],u2[8],xr[8];                                          \
        _Pragma("unroll")                                                       \
        for (int i_=0;i_<8;i_++){                                               \
            u0[i_]=Ub[q_][(i_*3+0)*256+tid]; u1[i_]=Ub[q_][(i_*3+1)*256+tid];   \
            u2[i_]=Ub[q_][(i_*3+2)*256+tid]; xr[i_]=b2f(Xb[q_][i_*256+tid]);    \
        }                                                                       \
        __builtin_amdgcn_sched_barrier(0);                                      \
        _Pragma("unroll")                                                       \
        for (int i_=0;i_<8;i_++){                                               \
            int ss_=(base_)+i_;                                                 \
            int t_ = d ? (L_SEQ-1-l0-ss_) : (l0+ss_);                           \
            float f_=sigm(u1[i_] + vf*c + bfv);                                 \
            c = f_*c + (1.f-f_)*u0[i_];                                         \
            float r_=sigm(u2[i_] + vr*c + brv);                                 \
            xout[((size_t)t_*BATCH + b)*NIN + dcol] = f2b(r_*c + (1.f-r_)*xr[i_]); \
        }                                                                       \
    }while(0)

    RSTAGE(0, 0);
    asm volatile("s_waitcnt vmcnt(0)" ::: "memory");
    __builtin_amdgcn_sched_barrier(0);
    __builtin_amdgcn_s_barrier();
    int ngrp = C >> 3;
    for (int g = 0; g < ngrp; ++g){
        int q = g & 1;
        if (g + 1 < ngrp){
            RSTAGE((g+1)*8, q^1);
            asm volatile("s_waitcnt vmcnt(15)" ::: "memory");
        } else {
            asm volatile("s_waitcnt vmcnt(8)" ::: "memory");
        }
        __builtin_amdgcn_sched_barrier(0);
        __builtin_amdgcn_s_barrier();
        RCOMP(g*8, q);
        __builtin_amdgcn_s_barrier();
    }
    carry[ch] = c;
#undef RSTAGE
#undef RCOMP
}

// ---------------- classifier: out[(b*L + l)*3 + j] = h[row l*8+b] @ Wcls + bcls
__global__ __launch_bounds__(256) void k_cls(const bf16* __restrict__ Xf, const float* __restrict__ Wc,
                                             const float* __restrict__ bc, float* __restrict__ out){
    int wave = threadIdx.x >> 6, lane = threadIdx.x & 63;
    int row = blockIdx.x*4 + wave;                  // row = l*8+b
    const bf16* xp = Xf + (size_t)row*NIN + lane*16;
    u16x8 v0 = *(const u16x8*)(xp);
    u16x8 v1 = *(const u16x8*)(xp + 8);
    float a0=0.f, a1=0.f, a2=0.f;
    #pragma unroll
    for (int i=0;i<16;i++){
        float xv = bits2f(i<8 ? v0[i&7] : v1[i&7]);
        int k = lane*16 + i;
        a0 += xv*Wc[k*3+0];
        a1 += xv*Wc[k*3+1];
        a2 += xv*Wc[k*3+2];
    }
    #pragma unroll
    for (int off=32; off; off>>=1){
        a0 += __shfl_down(a0, off);
        a1 += __shfl_down(a1, off);
        a2 += __shfl_down(a2, off);
    }
    if (lane == 0){
        int l = row >> 3, b = row & 7;
        float* op = out + ((size_t)b*L_SEQ + l)*3;
        op[0] = a0 + bc[0];
        op[1] = a1 + bc[1];
        op[2] = a2 + bc[2];
    }
}

// ----------------------------------------------------------------
extern "C" void kernel_launch(void* const* d_in, const int* in_sizes, int n_in,
                              void* d_out, int out_size, void* d_ws, size_t ws_size,
                              hipStream_t stream){
    (void)in_sizes; (void)n_in; (void)out_size;
    const float* X    = (const float*)d_in[0];
    const float* W[4]  = {(const float*)d_in[1],(const float*)d_in[4],(const float*)d_in[7],(const float*)d_in[10]};
    const float* wc[4] = {(const float*)d_in[2],(const float*)d_in[5],(const float*)d_in[8],(const float*)d_in[11]};
    const float* bb[4] = {(const float*)d_in[3],(const float*)d_in[6],(const float*)d_in[9],(const float*)d_in[12]};
    const float* Wcls = (const float*)d_in[13];
    const float* bcls = (const float*)d_in[14];
    float* out = (float*)d_out;

    // workspace layout:
    //   xA    bf16[16384*1024]  @ 0           33,554,432
    //   xB    bf16[16384*1024]  @ 33554432    33,554,432
    //   dxT   f32 [8*2048]      @ 67108864        65,536
    //   carry f32 [8192]        @ 67174400        32,768
    //   Wt0-2 bf16[3072*1024]   @ 67207168    3 x 6,291,456
    //   Ucb   f32 [C*2*8*1536]  @ 86081536    C*98,304   (C: 64..2048)
    char*  ws    = (char*)d_ws;
    bf16*  xA    = (bf16*)ws;
    bf16*  xB    = (bf16*)(ws + 33554432);
    float* dxT   = (float*)(ws + 67108864);
    float* carry = (float*)(ws + 67174400);
    bf16*  Wt[3] = {(bf16*)(ws + 67207168), (bf16*)(ws + 73498624), (bf16*)(ws + 79790080)};
    float* Ucb   = (float*)(ws + 86081536);
    const size_t NEEDED = 86081536ull + 64ull*98304ull;

    if (ws_size < NEEDED){
        float code = 1.0e6f + (float)((ws_size >> 20) > 9999 ? 9999 : (ws_size >> 20)) * 100.0f;
        k_code<<<1, 64, 0, stream>>>(out, code);
        return;
    }

    int C = 2048;
    while (C > 64 && 86081536ull + (size_t)C*98304ull > ws_size) C >>= 1;

    k_diff  <<<(NROWS+255)/256, 256, 0, stream>>>(X, dxT);
    for (int i = 0; i < 3; ++i)
        k_wt<<<dim3(32,96), 256, 0, stream>>>(W[i+1], Wt[i]);
    k_layer0<<<32, 256, 0, stream>>>(dxT, W[0], wc[0], bb[0], xA);

    bf16* xin = xA; bf16* xo = xB;
    for (int layer = 1; layer < 4; ++layer){
        for (int l0 = 0; l0 < L_SEQ; l0 += C){
            dim3 g(C*8/128, NHALF/128, 2);
            k_gemm<<<g, 256, 0, stream>>>(xin, Wt[layer-1], Ucb, l0, C);
            k_rec <<<32, 256, 0, stream>>>(Ucb, xin, xo, carry, wc[layer], bb[layer], l0, C);
        }
        bf16* t = xin; xin = xo; xo = t;
    }
    k_cls<<<NROWS/4, 256, 0, stream>>>(xin, Wcls, bcls, out);
}

// Round 13
// 1823.765 us; speedup vs baseline: 2.1361x; 1.0069x over previous
//
#include <hip/hip_runtime.h>
#include <hip/hip_bf16.h>

typedef __hip_bfloat16 bf16;
typedef unsigned short u16x8 __attribute__((ext_vector_type(8)));
using v8s = __attribute__((ext_vector_type(8))) short;   // bf16 x8 MFMA frag (4 VGPR)
using v4f = __attribute__((ext_vector_type(4))) float;   // f32 x4 acc frag

#define L_SEQ 2048
#define BATCH 8
#define NIN   1024    // 2H
#define WLD   3072    // W row stride, layers 1-3
#define NHALF 1536    // per-direction columns (3*H)
#define NROWS (L_SEQ*BATCH)

__device__ __forceinline__ float bits2f(unsigned short u){ return __uint_as_float(((unsigned)u)<<16); }
__device__ __forceinline__ float b2f(bf16 v){ return __bfloat162float(v); }
__device__ __forceinline__ bf16  f2b(float v){ return __float2bfloat16(v); }
__device__ __forceinline__ float sigm(float z){ return __fdividef(1.0f, 1.0f + __expf(-z)); }

__device__ __forceinline__ void gload16(const void* g, void* l){
    __builtin_amdgcn_global_load_lds((const __attribute__((address_space(1))) void*)g,
                                     (__attribute__((address_space(3))) void*)l, 16, 0, 0);
}

__global__ void k_code(float* __restrict__ out, float v){
    if (threadIdx.x == 0 && blockIdx.x == 0) out[0] = v;
}

// ---------------- dxT[b][l] = X[b][l] - X[b][l-1], 0 at l=0  ((B,L) layout)
__global__ __launch_bounds__(256) void k_diff(const float* __restrict__ X, float* __restrict__ dxT){
    int i = blockIdx.x*256 + threadIdx.x;
    if (i >= NROWS) return;
    int l = i & (L_SEQ-1);
    float v = 0.f;
    if (l > 0) v = X[i] - X[i-1];
    dxT[i] = v;
}

// ---------------- W (fp32 [1024][3072]) -> Wt (bf16 [3072][1024], transposed)
__global__ __launch_bounds__(256) void k_wt(const float* __restrict__ W, bf16* __restrict__ Wt){
    __shared__ float t[32][33];
    int k0 = blockIdx.x*32, n0 = blockIdx.y*32;
    int tx = threadIdx.x & 31, ty = threadIdx.x >> 5;   // ty 0..7
    #pragma unroll
    for (int j=0;j<4;j++)
        t[ty*4+j][tx] = W[(size_t)(k0+ty*4+j)*WLD + n0 + tx];
    __syncthreads();
    #pragma unroll
    for (int j=0;j<4;j++)
        Wt[(size_t)(n0+ty*4+j)*NIN + k0 + tx] = f2b(t[tx][ty*4+j]);
}

// ---------------- layer 0 (n_in=1, k=4): measured-252us version (32x256, pinned 8-ahead prefetch)
__global__ __launch_bounds__(256) void k_layer0(const float* __restrict__ dxT, const float* __restrict__ W0,
                                                const float* __restrict__ wc, const float* __restrict__ bb,
                                                bf16* __restrict__ xout){
    __shared__ float sdx[L_SEQ];
    int g = blockIdx.x*256 + threadIdx.x;           // 8192 threads: (d,b,h); b,d block-uniform
    int h = g & 511, b = (g>>9) & 7, d = g >> 12;
    const float* dxp = dxT + b*L_SEQ;
    for (int t = threadIdx.x; t < L_SEQ; t += 256) sdx[t] = dxp[t];
    __syncthreads();

    int dcol = d*512 + h;
    float w0 = W0[d*2048 + h];
    float w1 = W0[d*2048 + 512 + h];
    float w2 = W0[d*2048 + 1024 + h];
    float w3 = W0[d*2048 + 1536 + h];
    float vf = wc[dcol],  vr = wc[1024 + dcol];
    float bfv = bb[dcol], brv = bb[1024 + dcol];
    float c = 0.f;

#define LD0(buf, s0) do{                                             \
        _Pragma("unroll")                                            \
        for (int i_=0;i_<8;i_++){                                    \
            int ss_ = (s0)+i_; if (ss_ > L_SEQ-1) ss_ = L_SEQ-1;     \
            buf[i_] = sdx[d ? (L_SEQ-1-ss_) : ss_];                  \
        }                                                            \
        __builtin_amdgcn_sched_barrier(0);                           \
    }while(0)

#define STEP0(s_, xv_) do{                                           \
        float u0_ = (xv_)*w0;                                        \
        float f_ = sigm((xv_)*w1 + vf*c + bfv);                      \
        c = f_*c + (1.f-f_)*u0_;                                     \
        float r_ = sigm((xv_)*w2 + vr*c + brv);                      \
        float hv_ = r_*c + (1.f-r_)*((xv_)*w3);                      \
        int t_ = d ? (L_SEQ-1-(s_)) : (s_);                          \
        xout[((size_t)t_*BATCH + b)*NIN + dcol] = f2b(hv_);          \
    }while(0)

    float xa[8], xb[8];
    LD0(xa, 0);
    for (int s0 = 0; s0 < L_SEQ; s0 += 16){
        LD0(xb, s0+8);
        #pragma unroll
        for (int i=0;i<8;i++) STEP0(s0+i, xa[i]);
        LD0(xa, s0+16);
        #pragma unroll
        for (int i=0;i<8;i++) STEP0(s0+8+i, xb[i]);
    }
#undef LD0
#undef STEP0
}

// ---------------- MFMA GEMM: Uc[set s] = x[chunk rows] @ Wt[set s]^T
// 128x128 tile, BK=32, 4 waves, counted-vmcnt 2-phase dbuf.
// NEW: XOR bank-swizzle (rule #21): LDS dest stays linear; global SOURCE k-chunk is
// pre-swizzled by key=(row>>1)&3, and reads apply the same XOR -> 8-way conflict becomes 2-way (free).
__global__ __launch_bounds__(256) void k_gemm(const bf16* __restrict__ Xin, const bf16* __restrict__ Wt,
                                              float* __restrict__ Uc, int l0, int C){
    __shared__ bf16 As[2][4096];   // [buf][128 m][32 k], 64B rows
    __shared__ bf16 Bs[2][4096];
    int tid = threadIdx.x;
    int lane = tid & 63;
    int s = blockIdx.z;
    int base = (s == 0) ? l0 : (L_SEQ - l0 - C);
    const bf16* A  = Xin + (size_t)base*BATCH*NIN;
    const bf16* Bm = Wt + (size_t)s*NHALF*NIN;
    float*      Cc = Uc + (size_t)s*(size_t)C*BATCH*NHALF;

    int m0 = blockIdx.x*128, n0 = blockIdx.y*128;
    int wv = tid >> 6;
    int wm = (wv >> 1)*64, wn = (wv & 1)*64;

    v4f acc[4][4];
    #pragma unroll
    for (int i=0;i<4;i++)
        #pragma unroll
        for (int j=0;j<4;j++)
            #pragma unroll
            for (int r=0;r<4;r++) acc[i][j][r] = 0.f;

    int row_a = tid >> 2;
    // swizzled global k-chunk: slot (tid&3) XOR key((row_a>>1)&3 == (tid>>3)&3); row+64 keeps the key
    int kb = (((tid & 3) ^ ((tid >> 3) & 3)))*8;
    int wbase = (tid & 192)*16;
    // swizzled fragment read: slot (lane>>4) XOR key(((lane&15)>>1)&3); frag row base (mult of 16) keeps key
    int fro = (lane & 15)*64 + (((lane >> 4) ^ (((lane & 15) >> 1) & 3)))*16;

#define STAGE(q, k0) do{                                                        \
        char* la_ = (char*)As[q]; char* lb_ = (char*)Bs[q];                     \
        gload16(A  + (size_t)(m0 + row_a      )*NIN + (k0) + kb, la_ + wbase);  \
        gload16(A  + (size_t)(m0 + row_a + 64 )*NIN + (k0) + kb, la_ + 4096 + wbase); \
        gload16(Bm + (size_t)(n0 + row_a      )*NIN + (k0) + kb, lb_ + wbase);  \
        gload16(Bm + (size_t)(n0 + row_a + 64 )*NIN + (k0) + kb, lb_ + 4096 + wbase); \
    }while(0)

    STAGE(0, 0);
    int cur = 0;
    for (int k0 = 0; k0 < NIN; k0 += 32){
        if (k0 + 32 < NIN){
            STAGE(cur^1, k0 + 32);                              // 4 prefetch loads in flight
            asm volatile("s_waitcnt vmcnt(4)" ::: "memory");    // drain only tile-k loads
        } else {
            asm volatile("s_waitcnt vmcnt(0)" ::: "memory");
        }
        __builtin_amdgcn_sched_barrier(0);
        __builtin_amdgcn_s_barrier();      // tile k resident for all waves
        const char* la = (const char*)As[cur];
        const char* lb = (const char*)Bs[cur];
        v8s av[4], bv[4];
        #pragma unroll
        for (int i=0;i<4;i++) av[i] = *(const v8s*)(la + (wm + i*16)*64 + fro);
        #pragma unroll
        for (int j=0;j<4;j++) bv[j] = *(const v8s*)(lb + (wn + j*16)*64 + fro);
        #pragma unroll
        for (int i=0;i<4;i++)
            #pragma unroll
            for (int j=0;j<4;j++)
                acc[i][j] = __builtin_amdgcn_mfma_f32_16x16x32_bf16(av[i], bv[j], acc[i][j], 0, 0, 0);
        __builtin_amdgcn_s_barrier();      // all reads of buf cur done before restage
        cur ^= 1;
    }
#undef STAGE

    int cr = (lane >> 4)*4, ccol = lane & 15;
    #pragma unroll
    for (int i=0;i<4;i++){
        #pragma unroll
        for (int j=0;j<4;j++){
            size_t rb = (size_t)(m0 + wm + i*16 + cr)*NHALF + (n0 + wn + j*16 + ccol);
            #pragma unroll
            for (int r=0;r<4;r++) Cc[rb + (size_t)r*NHALF] = acc[i][j][r];
        }
    }
}

// ---------------- recurrence, layers 1-3: LDS-staged U/x via global_load_lds (round-11, validated)
__global__ __launch_bounds__(256) void k_rec(const float* __restrict__ Uc, const bf16* __restrict__ xin,
                                             bf16* __restrict__ xout, float* __restrict__ carry,
                                             const float* __restrict__ wc, const float* __restrict__ bb,
                                             int l0, int C){
    __shared__ float Ub[2][6144];   // [buf][seg=step*3+gate][256 floats]  2x24KB
    __shared__ bf16  Xb[2][2048];   // [buf][step][256 bf16]               2x4KB
    int tid = threadIdx.x;
    int lane = tid & 63, wv = tid >> 6;
    int bid = blockIdx.x;
    int d = bid >> 4, b = (bid >> 1) & 7, hbase = (bid & 1)*256;
    int h = hbase + tid;
    int dcol = d*512 + h;
    int ch = d*4096 + b*512 + h;
    float vf = wc[d*512 + h], vr = wc[1024 + d*512 + h];
    float bfv = bb[d*512 + h], brv = bb[1024 + d*512 + h];
    float c = (l0 == 0) ? 0.f : carry[ch];

    const float* Ubase = Uc + (size_t)d*(size_t)C*12288 + b*1536 + hbase;

#define RSTAGE(base_, q_) do{                                                   \
        char* ub_ = (char*)Ub[q_]; char* xb_ = (char*)Xb[q_];                   \
        _Pragma("unroll")                                                       \
        for (int qq=0; qq<6; ++qq){                                             \
            int seg = qq*4 + wv;                                                \
            int st_ = seg/3, gate_ = seg - st_*3;                               \
            int ss_ = (base_) + st_;                                            \
            int row_ = d ? (C-1-ss_) : ss_;                                     \
            gload16(Ubase + (size_t)row_*12288 + gate_*512 + lane*4,            \
                    ub_ + seg*1024);                                            \
        }                                                                       \
        {   int st_ = (base_) + 2*wv + (lane>>5);                               \
            int t_  = d ? (L_SEQ-1 - l0 - st_) : (l0 + st_);                    \
            gload16(xin + ((size_t)t_*BATCH + b)*NIN + d*512 + hbase + (lane&31)*8, \
                    xb_ + wv*1024);                                             \
        }                                                                       \
    }while(0)

#define RCOMP(base_, q_) do{                                                    \
        float u0[8],u1[8],u2[8],xr[8];                                          \
        _Pragma("unroll")                                                       \
        for (int i_=0;i_<8;i_++){                                               \
            u0[i_]=Ub[q_][(i_*3+0)*256+tid]; u1[i_]=Ub[q_][(i_*3+1)*256+tid];   \
            u2[i_]=Ub[q_][(i_*3+2)*256+tid]; xr[i_]=b2f(Xb[q_][i_*256+tid]);    \
        }                                                                       \
        __builtin_amdgcn_sched_barrier(0);                                      \
        _Pragma("unroll")                                                       \
        for (int i_=0;i_<8;i_++){                                               \
            int ss_=(base_)+i_;                                                 \
            int t_ = d ? (L_SEQ-1-l0-ss_) : (l0+ss_);                           \
            float f_=sigm(u1[i_] + vf*c + bfv);                                 \
            c = f_*c + (1.f-f_)*u0[i_];                                         \
            float r_=sigm(u2[i_] + vr*c + brv);                                 \
            xout[((size_t)t_*BATCH + b)*NIN + dcol] = f2b(r_*c + (1.f-r_)*xr[i_]); \
        }                                                                       \
    }while(0)

    RSTAGE(0, 0);
    asm volatile("s_waitcnt vmcnt(0)" ::: "memory");
    __builtin_amdgcn_sched_barrier(0);
    __builtin_amdgcn_s_barrier();
    int ngrp = C >> 3;
    for (int g = 0; g < ngrp; ++g){
        int q = g & 1;
        if (g + 1 < ngrp){
            RSTAGE((g+1)*8, q^1);
            asm volatile("s_waitcnt vmcnt(15)" ::: "memory");
        } else {
            asm volatile("s_waitcnt vmcnt(8)" ::: "memory");
        }
        __builtin_amdgcn_sched_barrier(0);
        __builtin_amdgcn_s_barrier();
        RCOMP(g*8, q);
        __builtin_amdgcn_s_barrier();
    }
    carry[ch] = c;
#undef RSTAGE
#undef RCOMP
}

// ---------------- classifier: out[(b*L + l)*3 + j] = h[row l*8+b] @ Wcls + bcls
__global__ __launch_bounds__(256) void k_cls(const bf16* __restrict__ Xf, const float* __restrict__ Wc,
                                             const float* __restrict__ bc, float* __restrict__ out){
    int wave = threadIdx.x >> 6, lane = threadIdx.x & 63;
    int row = blockIdx.x*4 + wave;                  // row = l*8+b
    const bf16* xp = Xf + (size_t)row*NIN + lane*16;
    u16x8 v0 = *(const u16x8*)(xp);
    u16x8 v1 = *(const u16x8*)(xp + 8);
    float a0=0.f, a1=0.f, a2=0.f;
    #pragma unroll
    for (int i=0;i<16;i++){
        float xv = bits2f(i<8 ? v0[i&7] : v1[i&7]);
        int k = lane*16 + i;
        a0 += xv*Wc[k*3+0];
        a1 += xv*Wc[k*3+1];
        a2 += xv*Wc[k*3+2];
    }
    #pragma unroll
    for (int off=32; off; off>>=1){
        a0 += __shfl_down(a0, off);
        a1 += __shfl_down(a1, off);
        a2 += __shfl_down(a2, off);
    }
    if (lane == 0){
        int l = row >> 3, b = row & 7;
        float* op = out + ((size_t)b*L_SEQ + l)*3;
        op[0] = a0 + bc[0];
        op[1] = a1 + bc[1];
        op[2] = a2 + bc[2];
    }
}

// ----------------------------------------------------------------
extern "C" void kernel_launch(void* const* d_in, const int* in_sizes, int n_in,
                              void* d_out, int out_size, void* d_ws, size_t ws_size,
                              hipStream_t stream){
    (void)in_sizes; (void)n_in; (void)out_size;
    const float* X    = (const float*)d_in[0];
    const float* W[4]  = {(const float*)d_in[1],(const float*)d_in[4],(const float*)d_in[7],(const float*)d_in[10]};
    const float* wc[4] = {(const float*)d_in[2],(const float*)d_in[5],(const float*)d_in[8],(const float*)d_in[11]};
    const float* bb[4] = {(const float*)d_in[3],(const float*)d_in[6],(const float*)d_in[9],(const float*)d_in[12]};
    const float* Wcls = (const float*)d_in[13];
    const float* bcls = (const float*)d_in[14];
    float* out = (float*)d_out;

    // workspace layout:
    //   xA    bf16[16384*1024]  @ 0           33,554,432
    //   xB    bf16[16384*1024]  @ 33554432    33,554,432
    //   dxT   f32 [8*2048]      @ 67108864        65,536
    //   carry f32 [8192]        @ 67174400        32,768
    //   Wt0-2 bf16[3072*1024]   @ 67207168    3 x 6,291,456
    //   Ucb   f32 [C*2*8*1536]  @ 86081536    C*98,304   (C: 64..2048)
    char*  ws    = (char*)d_ws;
    bf16*  xA    = (bf16*)ws;
    bf16*  xB    = (bf16*)(ws + 33554432);
    float* dxT   = (float*)(ws + 67108864);
    float* carry = (float*)(ws + 67174400);
    bf16*  Wt[3] = {(bf16*)(ws + 67207168), (bf16*)(ws + 73498624), (bf16*)(ws + 79790080)};
    float* Ucb   = (float*)(ws + 86081536);
    const size_t NEEDED = 86081536ull + 64ull*98304ull;

    if (ws_size < NEEDED){
        float code = 1.0e6f + (float)((ws_size >> 20) > 9999 ? 9999 : (ws_size >> 20)) * 100.0f;
        k_code<<<1, 64, 0, stream>>>(out, code);
        return;
    }

    int C = 2048;
    while (C > 64 && 86081536ull + (size_t)C*98304ull > ws_size) C >>= 1;

    k_diff  <<<(NROWS+255)/256, 256, 0, stream>>>(X, dxT);
    for (int i = 0; i < 3; ++i)
        k_wt<<<dim3(32,96), 256, 0, stream>>>(W[i+1], Wt[i]);
    k_layer0<<<32, 256, 0, stream>>>(dxT, W[0], wc[0], bb[0], xA);

    bf16* xin = xA; bf16* xo = xB;
    for (int layer = 1; layer < 4; ++layer){
        for (int l0 = 0; l0 < L_SEQ; l0 += C){
            dim3 g(C*8/128, NHALF/128, 2);
            k_gemm<<<g, 256, 0, stream>>>(xin, Wt[layer-1], Ucb, l0, C);
            k_rec <<<32, 256, 0, stream>>>(Ucb, xin, xo, carry, wc[layer], bb[layer], l0, C);
        }
        bf16* t = xin; xin = xo; xo = t;
    }
    k_cls<<<NROWS/4, 256, 0, stream>>>(xin, Wcls, bcls, out);
}